// Round 2
// baseline (6025.789 us; speedup 1.0000x reference)
//
#include <hip/hip_runtime.h>

typedef unsigned short u16;
typedef __attribute__((ext_vector_type(8))) short bf16x8;
typedef __attribute__((ext_vector_type(4))) float f32x4;
typedef __attribute__((ext_vector_type(16))) float f32x16;

#define MFMA16(a, b, c) __builtin_amdgcn_mfma_f32_16x16x32_bf16((a), (b), (c), 0, 0, 0)
#define MFMA32(a, b, c) __builtin_amdgcn_mfma_f32_32x32x16_bf16((a), (b), (c), 0, 0, 0)

// ---- problem sizes ----
#define TT 128
#define BB 128
#define IN_ 512
#define HH 512
#define G4 2048   // 4*H
#define OUTD 512
#define TB 16384  // T*B

__device__ __forceinline__ u16 f2bf(float f) {
    union { float f; unsigned u; } v; v.f = f;
    unsigned r = v.u + 0x7FFFu + ((v.u >> 16) & 1u);
    return (u16)(r >> 16);
}
__device__ __forceinline__ float bf2f(u16 h) {
    union { unsigned u; float f; } v; v.u = ((unsigned)h) << 16; return v.f;
}
__device__ __forceinline__ float sigmoid_f(float x) { return 1.f / (1.f + __expf(-x)); }
__device__ __forceinline__ float tanh_f(float x) {
    float e = __expf(2.f * x);
    return 1.f - 2.f / (e + 1.f);
}

// ---- fp32 -> bf16 convert (vectorized) ----
__global__ void cvt_kernel(const float* __restrict__ src, u16* __restrict__ dst, int n4) {
    int i = blockIdx.x * blockDim.x + threadIdx.x;
    int stride = gridDim.x * blockDim.x;
    for (; i < n4; i += stride) {
        float4 v = ((const float4*)src)[i];
        ushort4 o;
        o.x = f2bf(v.x); o.y = f2bf(v.y); o.z = f2bf(v.z); o.w = f2bf(v.w);
        ((ushort4*)dst)[i] = o;
    }
}

__global__ void bias_kernel(const float* __restrict__ bihf, const float* __restrict__ bhhf,
                            float* __restrict__ bf_, const float* __restrict__ bihb,
                            const float* __restrict__ bhhb, float* __restrict__ bb_, int n) {
    int i = blockIdx.x * blockDim.x + threadIdx.x;
    if (i < n) {
        bf_[i] = bihf[i] + bhhf[i];
        bb_[i] = bihb[i] + bhhb[i];
    }
}

// ---- generic 128x128-tile bf16 MFMA GEMM: C[M,N] = A[M,K] * W[N,K]^T + bias[N] ----
__global__ __launch_bounds__(256) void gemm_bias_kernel(
    const u16* __restrict__ A, const u16* __restrict__ W,
    const float* __restrict__ bias, void* __restrict__ Cout,
    int M, int N, int K, int out_is_bf16) {
    __shared__ __align__(16) u16 lA[128 * 72];
    __shared__ __align__(16) u16 lB[128 * 72];
    const int tid = threadIdx.x;
    const int m0 = blockIdx.x * 128;
    const int n0 = blockIdx.y * 128;
    const int wave = tid >> 6, lane = tid & 63;
    const int wm = wave >> 1, wn = wave & 1;
    const int lrow = lane & 15, lq = lane >> 4;

    f32x4 acc[4][4] = {};

    for (int kc = 0; kc < K; kc += 64) {
        #pragma unroll
        for (int i = 0; i < 4; ++i) {
            int c = i * 256 + tid;
            int row = c >> 3, off = c & 7;
            *(uint4*)(&lA[row * 72 + off * 8]) =
                *(const uint4*)(&A[(size_t)(m0 + row) * K + kc + off * 8]);
            *(uint4*)(&lB[row * 72 + off * 8]) =
                *(const uint4*)(&W[(size_t)(n0 + row) * K + kc + off * 8]);
        }
        __syncthreads();
        #pragma unroll
        for (int ks = 0; ks < 2; ++ks) {
            bf16x8 af[4], bfr[4];
            #pragma unroll
            for (int mf = 0; mf < 4; ++mf)
                af[mf] = *(const bf16x8*)(&lA[(wm * 64 + mf * 16 + lrow) * 72 + ks * 32 + lq * 8]);
            #pragma unroll
            for (int nf = 0; nf < 4; ++nf)
                bfr[nf] = *(const bf16x8*)(&lB[(wn * 64 + nf * 16 + lrow) * 72 + ks * 32 + lq * 8]);
            #pragma unroll
            for (int mf = 0; mf < 4; ++mf)
                #pragma unroll
                for (int nf = 0; nf < 4; ++nf)
                    acc[mf][nf] = MFMA16(af[mf], bfr[nf], acc[mf][nf]);
        }
        __syncthreads();
    }

    #pragma unroll
    for (int mf = 0; mf < 4; ++mf) {
        #pragma unroll
        for (int nf = 0; nf < 4; ++nf) {
            int row = m0 + wm * 64 + mf * 16 + lq * 4;
            int col = n0 + wn * 64 + nf * 16 + lrow;
            float bv = bias[col];
            f32x4 v = acc[mf][nf];
            #pragma unroll
            for (int r = 0; r < 4; ++r) {
                float val = v[r] + bv;
                if (out_is_bf16)
                    ((u16*)Cout)[(size_t)(row + r) * N + col] = f2bf(val);
                else
                    ((float*)Cout)[(size_t)(row + r) * N + col] = val;
            }
        }
    }
}

// ---- persistent recurrence kernel: all 128 timesteps, one launch ----
// 256 blocks x 256 threads. blockIdx = jt*8 + g, g = dir*4 + bi (group on one XCD).
// Block owns: batch rows [bi*32, +32), gate-cols {gate*512 + jt*16 + 0..15, gate=0..3}.
// W slice (64 rows x 512) lives in VGPRs for the whole kernel; c-state in VGPRs.
// Per step: read group's h_prev (32KB) -> LDS, 2-way-K-split 32x32x16 MFMA,
// LDS partial reduce, pointwise, write h (1KB), group barrier (32 blocks, atomic ctr).
__global__ __launch_bounds__(256) void lstm_seq_kernel(
    const u16* __restrict__ xw_f, const u16* __restrict__ xw_b,
    const u16* __restrict__ whh_f, const u16* __restrict__ whh_b,
    u16* __restrict__ hcat, unsigned* __restrict__ ctrs) {
    const int g   = blockIdx.x & 7;
    const int jt  = blockIdx.x >> 3;
    const int dir = g >> 2;
    const int bi  = g & 3;
    const int b0  = bi * 32;
    const int j0  = jt * 16;
    const u16* __restrict__ xw  = dir ? xw_b : xw_f;
    const u16* __restrict__ whh = dir ? whh_b : whh_f;
    unsigned* ctr = ctrs + g * 64;   // 256B apart, one per group

    __shared__ __align__(16) u16 lh[32 * 520];     // h_prev [32 x 512], stride 520 shorts
    __shared__ float part[2][32][64];              // k-split partials

    const int tid  = threadIdx.x;
    const int wave = tid >> 6, lane = tid & 63;
    const int nl = lane & 31, kh = lane >> 5;
    const int nw  = wave >> 1;       // n-tile (0: cols 0..31 = gates i,f; 1: cols 32..63 = g,o)
    const int kw2 = wave & 1;        // k-strip of 256

    // persistent W fragments: 16 x bf16x8 = 64 VGPRs/lane
    // local col c -> W row: (c>>4)*512 + j0 + (c&15)
    bf16x8 Wf[16];
    {
        int c = nw * 32 + nl;
        const u16* wr = whh + (size_t)((c >> 4) * 512 + j0 + (c & 15)) * 512;
        #pragma unroll
        for (int kk = 0; kk < 16; ++kk)
            Wf[kk] = *(const bf16x8*)(&wr[kw2 * 256 + kk * 16 + kh * 8]);
    }

    // cell state: thread owns cells tid and tid+256 (cell e: b = e>>4, j = e&15)
    float c0 = 0.f, c1 = 0.f;

    for (int s = 0; s < TT; ++s) {
        const int t = dir ? (TT - 1 - s) : s;
        f32x16 acc = {};
        if (s > 0) {
            const int tp = dir ? (t + 1) : (t - 1);
            const u16* hsrc = hcat + ((size_t)tp * BB + b0) * (2 * HH) + dir * HH;
            {
                int row = tid >> 3, seg = tid & 7;   // each thread: 128B of one row
                const uint4* gs = (const uint4*)(hsrc + (size_t)row * (2 * HH) + seg * 64);
                uint4* ld = (uint4*)(&lh[row * 520 + seg * 64]);
                #pragma unroll
                for (int i = 0; i < 8; ++i) ld[i] = gs[i];
            }
            __syncthreads();
            #pragma unroll
            for (int kk = 0; kk < 16; ++kk) {
                bf16x8 a = *(const bf16x8*)(&lh[nl * 520 + kw2 * 256 + kk * 16 + kh * 8]);
                acc = MFMA32(a, Wf[kk], acc);
            }
        }
        // partials: D layout col=lane&31, row=(reg&3)+8*(reg>>2)+4*(lane>>5)
        #pragma unroll
        for (int r = 0; r < 16; ++r) {
            int row = (r & 3) + 8 * (r >> 2) + 4 * kh;
            part[kw2][row][nw * 32 + nl] = acc[r];
        }
        __syncthreads();

        // pointwise: 2 cells per thread
        #pragma unroll
        for (int e = 0; e < 2; ++e) {
            int cell = tid + e * 256;
            int b = cell >> 4, j = cell & 15;
            size_t xb = ((size_t)t * BB + b0 + b) * G4 + j0 + j;
            float gv[4];
            #pragma unroll
            for (int gg = 0; gg < 4; ++gg) {
                int colc = gg * 16 + j;
                gv[gg] = part[0][b][colc] + part[1][b][colc]
                       + bf2f(xw[xb + (size_t)gg * HH]);
            }
            float iv  = sigmoid_f(gv[0]);
            float fv  = sigmoid_f(gv[1]);
            float ggv = tanh_f(gv[2]);
            float ov  = sigmoid_f(gv[3]);
            float cprev = e ? c1 : c0;
            float cn = fv * cprev + iv * ggv;
            if (e) c1 = cn; else c0 = cn;
            float hn = ov * tanh_f(cn);
            hcat[((size_t)t * BB + b0 + b) * (2 * HH) + dir * HH + j0 + j] = f2bf(hn);
        }

        if (s < TT - 1) {
            __threadfence();          // release this thread's h stores (device scope)
            __syncthreads();
            if (tid == 0) {
                __hip_atomic_fetch_add(ctr, 1u, __ATOMIC_RELEASE, __HIP_MEMORY_SCOPE_AGENT);
                unsigned tgt = 32u * (unsigned)(s + 1);   // monotonic counter, no reset
                while (__hip_atomic_load(ctr, __ATOMIC_ACQUIRE, __HIP_MEMORY_SCOPE_AGENT) < tgt)
                    __builtin_amdgcn_s_sleep(1);
            }
            __syncthreads();
            __threadfence();          // acquire side: invalidate caches before reading fresh h
        }
    }
}

// ---- workspace layout (bytes) ----
#define OFF_XBF    ((size_t)0)
#define OFF_WIHF   (OFF_XBF  + (size_t)TB * IN_ * 2)
#define OFF_WIHB   (OFF_WIHF + (size_t)G4 * IN_ * 2)
#define OFF_WHHF   (OFF_WIHB + (size_t)G4 * IN_ * 2)
#define OFF_WHHB   (OFF_WHHF + (size_t)G4 * HH * 2)
#define OFF_WLIN   (OFF_WHHB + (size_t)G4 * HH * 2)
#define OFF_BIASF  (OFF_WLIN + (size_t)OUTD * 2 * HH * 2)
#define OFF_BIASB  (OFF_BIASF + (size_t)G4 * 4)
#define OFF_XWF    (OFF_BIASB + (size_t)G4 * 4)
#define OFF_XWB    (OFF_XWF  + (size_t)TB * G4 * 2)
#define OFF_HCAT   (OFF_XWB  + (size_t)TB * G4 * 2)
#define OFF_CF     (OFF_HCAT + (size_t)TB * 2 * HH * 2)
#define OFF_CB     (OFF_CF   + (size_t)BB * HH * 4)
#define OFF_CTR    (OFF_CB   + (size_t)BB * HH * 4)
#define WS_NEED    (OFF_CTR  + (size_t)8 * 64 * 4)

extern "C" void kernel_launch(void* const* d_in, const int* in_sizes, int n_in,
                              void* d_out, int out_size, void* d_ws, size_t ws_size,
                              hipStream_t stream) {
    (void)in_sizes; (void)n_in; (void)out_size;
    if (ws_size < WS_NEED) return;

    const float* x    = (const float*)d_in[0];
    const float* Wihf = (const float*)d_in[1];
    const float* Whhf = (const float*)d_in[2];
    const float* bihf = (const float*)d_in[3];
    const float* bhhf = (const float*)d_in[4];
    const float* Wihb = (const float*)d_in[5];
    const float* Whhb = (const float*)d_in[6];
    const float* bihb = (const float*)d_in[7];
    const float* bhhb = (const float*)d_in[8];
    const float* Wlin = (const float*)d_in[9];
    const float* blin = (const float*)d_in[10];
    float* out = (float*)d_out;

    char* ws = (char*)d_ws;
    u16* x_bf    = (u16*)(ws + OFF_XBF);
    u16* wihf_bf = (u16*)(ws + OFF_WIHF);
    u16* wihb_bf = (u16*)(ws + OFF_WIHB);
    u16* whhf_bf = (u16*)(ws + OFF_WHHF);
    u16* whhb_bf = (u16*)(ws + OFF_WHHB);
    u16* wlin_bf = (u16*)(ws + OFF_WLIN);
    float* bias_f = (float*)(ws + OFF_BIASF);
    float* bias_b = (float*)(ws + OFF_BIASB);
    u16* xw_f = (u16*)(ws + OFF_XWF);
    u16* xw_b = (u16*)(ws + OFF_XWB);
    u16* hcat = (u16*)(ws + OFF_HCAT);
    unsigned* ctrs = (unsigned*)(ws + OFF_CTR);

    cvt_kernel<<<2048, 256, 0, stream>>>(x, x_bf, (TB * IN_) / 4);
    cvt_kernel<<<512, 256, 0, stream>>>(Wihf, wihf_bf, (G4 * IN_) / 4);
    cvt_kernel<<<512, 256, 0, stream>>>(Wihb, wihb_bf, (G4 * IN_) / 4);
    cvt_kernel<<<512, 256, 0, stream>>>(Whhf, whhf_bf, (G4 * HH) / 4);
    cvt_kernel<<<512, 256, 0, stream>>>(Whhb, whhb_bf, (G4 * HH) / 4);
    cvt_kernel<<<512, 256, 0, stream>>>(Wlin, wlin_bf, (OUTD * 2 * HH) / 4);
    bias_kernel<<<8, 256, 0, stream>>>(bihf, bhhf, bias_f, bihb, bhhb, bias_b, G4);

    // phase 1: xw = x @ W_ih^T + (b_ih + b_hh), bf16 out
    gemm_bias_kernel<<<dim3(TB / 128, G4 / 128), 256, 0, stream>>>(
        x_bf, wihf_bf, bias_f, xw_f, TB, G4, IN_, 1);
    gemm_bias_kernel<<<dim3(TB / 128, G4 / 128), 256, 0, stream>>>(
        x_bf, wihb_bf, bias_b, xw_b, TB, G4, IN_, 1);

    // phase 2: persistent recurrence (one launch, 128 steps, group-local barriers)
    hipMemsetAsync(ctrs, 0, 8 * 64 * 4, stream);
    lstm_seq_kernel<<<256, 256, 0, stream>>>(xw_f, xw_b, whhf_bf, whhb_bf, hcat, ctrs);

    // phase 3: out = hcat @ W_lin^T + b_lin, fp32 out
    gemm_bias_kernel<<<dim3(TB / 128, OUTD / 128), 256, 0, stream>>>(
        hcat, wlin_bf, blin, out, TB, OUTD, 2 * HH, 0);
}

// Round 5
// 1330.468 us; speedup vs baseline: 4.5291x; 4.5291x over previous
//
#include <hip/hip_runtime.h>

typedef unsigned short u16;
typedef unsigned long long u64;
typedef __attribute__((ext_vector_type(8))) short bf16x8;
typedef __attribute__((ext_vector_type(4))) float f32x4;
typedef __attribute__((ext_vector_type(16))) float f32x16;

#define MFMA16(a, b, c) __builtin_amdgcn_mfma_f32_16x16x32_bf16((a), (b), (c), 0, 0, 0)
#define MFMA32(a, b, c) __builtin_amdgcn_mfma_f32_32x32x16_bf16((a), (b), (c), 0, 0, 0)
#define WAITVM() asm volatile("s_waitcnt vmcnt(0)" ::: "memory")

// ---- problem sizes ----
#define TT 128
#define BB 128
#define IN_ 512
#define HH 512
#define G4 2048   // 4*H
#define OUTD 512
#define TB 16384  // T*B

__device__ __forceinline__ u16 f2bf(float f) {
    union { float f; unsigned u; } v; v.f = f;
    unsigned r = v.u + 0x7FFFu + ((v.u >> 16) & 1u);
    return (u16)(r >> 16);
}
__device__ __forceinline__ float bf2f(u16 h) {
    union { unsigned u; float f; } v; v.u = ((unsigned)h) << 16; return v.f;
}
__device__ __forceinline__ float sigmoid_f(float x) { return 1.f / (1.f + __expf(-x)); }
__device__ __forceinline__ float tanh_f(float x) {
    float e = __expf(2.f * x);
    return 1.f - 2.f / (e + 1.f);
}

// ---- fp32 -> bf16 convert (vectorized) ----
__global__ void cvt_kernel(const float* __restrict__ src, u16* __restrict__ dst, int n4) {
    int i = blockIdx.x * blockDim.x + threadIdx.x;
    int stride = gridDim.x * blockDim.x;
    for (; i < n4; i += stride) {
        float4 v = ((const float4*)src)[i];
        ushort4 o;
        o.x = f2bf(v.x); o.y = f2bf(v.y); o.z = f2bf(v.z); o.w = f2bf(v.w);
        ((ushort4*)dst)[i] = o;
    }
}

__global__ void bias_kernel(const float* __restrict__ bihf, const float* __restrict__ bhhf,
                            float* __restrict__ bf_, const float* __restrict__ bihb,
                            const float* __restrict__ bhhb, float* __restrict__ bb_, int n) {
    int i = blockIdx.x * blockDim.x + threadIdx.x;
    if (i < n) {
        bf_[i] = bihf[i] + bhhf[i];
        bb_[i] = bihb[i] + bhhb[i];
    }
}

// ---- generic 128x128-tile bf16 MFMA GEMM: C[M,N] = A[M,K] * W[N,K]^T + bias[N] ----
__global__ __launch_bounds__(256) void gemm_bias_kernel(
    const u16* __restrict__ A, const u16* __restrict__ W,
    const float* __restrict__ bias, void* __restrict__ Cout,
    int M, int N, int K, int out_is_bf16) {
    __shared__ __align__(16) u16 lA[128 * 72];
    __shared__ __align__(16) u16 lB[128 * 72];
    const int tid = threadIdx.x;
    const int m0 = blockIdx.x * 128;
    const int n0 = blockIdx.y * 128;
    const int wave = tid >> 6, lane = tid & 63;
    const int wm = wave >> 1, wn = wave & 1;
    const int lrow = lane & 15, lq = lane >> 4;

    f32x4 acc[4][4] = {};

    for (int kc = 0; kc < K; kc += 64) {
        #pragma unroll
        for (int i = 0; i < 4; ++i) {
            int c = i * 256 + tid;
            int row = c >> 3, off = c & 7;
            *(uint4*)(&lA[row * 72 + off * 8]) =
                *(const uint4*)(&A[(size_t)(m0 + row) * K + kc + off * 8]);
            *(uint4*)(&lB[row * 72 + off * 8]) =
                *(const uint4*)(&W[(size_t)(n0 + row) * K + kc + off * 8]);
        }
        __syncthreads();
        #pragma unroll
        for (int ks = 0; ks < 2; ++ks) {
            bf16x8 af[4], bfr[4];
            #pragma unroll
            for (int mf = 0; mf < 4; ++mf)
                af[mf] = *(const bf16x8*)(&lA[(wm * 64 + mf * 16 + lrow) * 72 + ks * 32 + lq * 8]);
            #pragma unroll
            for (int nf = 0; nf < 4; ++nf)
                bfr[nf] = *(const bf16x8*)(&lB[(wn * 64 + nf * 16 + lrow) * 72 + ks * 32 + lq * 8]);
            #pragma unroll
            for (int mf = 0; mf < 4; ++mf)
                #pragma unroll
                for (int nf = 0; nf < 4; ++nf)
                    acc[mf][nf] = MFMA16(af[mf], bfr[nf], acc[mf][nf]);
        }
        __syncthreads();
    }

    #pragma unroll
    for (int mf = 0; mf < 4; ++mf) {
        #pragma unroll
        for (int nf = 0; nf < 4; ++nf) {
            int row = m0 + wm * 64 + mf * 16 + lq * 4;
            int col = n0 + wn * 64 + nf * 16 + lrow;
            float bv = bias[col];
            f32x4 v = acc[mf][nf];
            #pragma unroll
            for (int r = 0; r < 4; ++r) {
                float val = v[r] + bv;
                if (out_is_bf16)
                    ((u16*)Cout)[(size_t)(row + r) * N + col] = f2bf(val);
                else
                    ((float*)Cout)[(size_t)(row + r) * N + col] = val;
            }
        }
    }
}

// ---- persistent recurrence kernel: all 128 timesteps, one launch ----
// 256 blocks x 256 threads. blockIdx = jt*8 + g, g = dir*4 + bi.
// Block: batch rows [bi*32,+32), gate-cols {gate*512 + jt*16 + 0..15}.
// W slice in VGPRs; c-state in VGPRs. ALL cross-block traffic goes through
// the L3 coherence point: h writes = u32 atomic exchange (RMW), h reads =
// u64 relaxed agent atomic loads, barrier = per-group monotone RMW counter
// (Round-2-proven). No cache-wide fences anywhere.
__global__ __launch_bounds__(256) void lstm_seq_kernel(
    const u16* __restrict__ xw_f, const u16* __restrict__ xw_b,
    const u16* __restrict__ whh_f, const u16* __restrict__ whh_b,
    u16* __restrict__ hcat, unsigned* __restrict__ ctrs) {
    const int g   = blockIdx.x & 7;
    const int jt  = blockIdx.x >> 3;
    const int dir = g >> 2;
    const int bi  = g & 3;
    const int b0  = bi * 32;
    const int j0  = jt * 16;
    const u16* __restrict__ xw  = dir ? xw_b : xw_f;
    const u16* __restrict__ whh = dir ? whh_b : whh_f;
    unsigned* ctr = ctrs + g * 64;   // one counter per group, 256B apart

    __shared__ __align__(16) u16 lh[32 * 520];   // h_prev [32 x 512]
    __shared__ float part[2][32][66];            // k-split partials (padded)

    const int tid  = threadIdx.x;
    const int wave = tid >> 6, lane = tid & 63;
    const int nl = lane & 31, kh = lane >> 5;
    const int nw  = wave >> 1;       // n-tile: cols 0..31 / 32..63
    const int kw2 = wave & 1;        // k-strip of 256

    // persistent W fragments: local col c -> W row (c>>4)*512 + j0 + (c&15)
    bf16x8 Wf[16];
    {
        int c = nw * 32 + nl;
        const u16* wr = whh + (size_t)((c >> 4) * 512 + j0 + (c & 15)) * 512;
        #pragma unroll
        for (int kk = 0; kk < 16; ++kk)
            Wf[kk] = *(const bf16x8*)(&wr[kw2 * 256 + kk * 16 + kh * 8]);
    }

    // pointwise mapping: thread owns (b=pb, j=pj) and (pb, pj+1)
    const int pb = tid >> 3, pj = (tid & 7) * 2;
    float cst0 = 0.f, cst1 = 0.f;

    for (int s = 0; s < TT; ++s) {
        const int t = dir ? (TT - 1 - s) : s;

        // prefetch xw gate values (cacheable; overlaps h staging + MFMA)
        const unsigned* xwp = (const unsigned*)(xw + ((size_t)t * BB + b0 + pb) * G4 + j0 + pj);
        unsigned xg0 = xwp[0];        // gate i  (gate stride 512 u16 = 256 u32)
        unsigned xg1 = xwp[256];      // gate f
        unsigned xg2 = xwp[512];      // gate g
        unsigned xg3 = xwp[768];      // gate o

        f32x16 acc = {};
        if (s > 0) {
            // stage h_prev [32 x 512] via L3-coherent u64 atomic loads
            const int tp = dir ? (t + 1) : (t - 1);
            const u16* hsrc = hcat + ((size_t)tp * BB + b0) * (2 * HH) + dir * HH;
            {
                int row = tid >> 3, seg = tid & 7;     // 128B per thread
                const u64* src = (const u64*)(hsrc + (size_t)row * (2 * HH) + seg * 64);
                u64* ld = (u64*)(&lh[row * 520 + seg * 64]);
                #pragma unroll
                for (int i = 0; i < 16; ++i)
                    ld[i] = __hip_atomic_load(&src[i], __ATOMIC_RELAXED,
                                              __HIP_MEMORY_SCOPE_AGENT);
            }
            __syncthreads();
            #pragma unroll
            for (int kk = 0; kk < 16; ++kk) {
                bf16x8 a = *(const bf16x8*)(&lh[nl * 520 + kw2 * 256 + kk * 16 + kh * 8]);
                acc = MFMA32(a, Wf[kk], acc);
            }
        }
        // partials: D layout col=lane&31, row=(reg&3)+8*(reg>>2)+4*(lane>>5)
        #pragma unroll
        for (int r = 0; r < 16; ++r) {
            int row = (r & 3) + 8 * (r >> 2) + 4 * kh;
            part[kw2][row][nw * 32 + nl] = acc[r];
        }
        __syncthreads();

        // pointwise: 2 adjacent cells -> one u32 atomic-exchange h store (at L3)
        {
            float g0a = part[0][pb][0 * 16 + pj]     + part[1][pb][0 * 16 + pj]     + bf2f((u16)(xg0 & 0xffff));
            float g0b = part[0][pb][0 * 16 + pj + 1] + part[1][pb][0 * 16 + pj + 1] + bf2f((u16)(xg0 >> 16));
            float g1a = part[0][pb][1 * 16 + pj]     + part[1][pb][1 * 16 + pj]     + bf2f((u16)(xg1 & 0xffff));
            float g1b = part[0][pb][1 * 16 + pj + 1] + part[1][pb][1 * 16 + pj + 1] + bf2f((u16)(xg1 >> 16));
            float g2a = part[0][pb][2 * 16 + pj]     + part[1][pb][2 * 16 + pj]     + bf2f((u16)(xg2 & 0xffff));
            float g2b = part[0][pb][2 * 16 + pj + 1] + part[1][pb][2 * 16 + pj + 1] + bf2f((u16)(xg2 >> 16));
            float g3a = part[0][pb][3 * 16 + pj]     + part[1][pb][3 * 16 + pj]     + bf2f((u16)(xg3 & 0xffff));
            float g3b = part[0][pb][3 * 16 + pj + 1] + part[1][pb][3 * 16 + pj + 1] + bf2f((u16)(xg3 >> 16));

            float cn0 = sigmoid_f(g1a) * cst0 + sigmoid_f(g0a) * tanh_f(g2a);
            float cn1 = sigmoid_f(g1b) * cst1 + sigmoid_f(g0b) * tanh_f(g2b);
            cst0 = cn0; cst1 = cn1;
            float h0 = sigmoid_f(g3a) * tanh_f(cn0);
            float h1 = sigmoid_f(g3b) * tanh_f(cn1);
            unsigned hval = (unsigned)f2bf(h0) | ((unsigned)f2bf(h1) << 16);
            unsigned* hp = (unsigned*)(hcat + ((size_t)t * BB + b0 + pb) * (2 * HH) + dir * HH + j0 + pj);
            (void)__hip_atomic_exchange(hp, hval, __ATOMIC_RELAXED,
                                        __HIP_MEMORY_SCOPE_AGENT);
        }

        if (s < TT - 1) {
            WAITVM();                 // this wave's h-exchanges are complete at L3
            __syncthreads();          // -> whole block's h tile is at L3
            if (tid == 0) {
                __hip_atomic_fetch_add(ctr, 1u, __ATOMIC_RELAXED,
                                       __HIP_MEMORY_SCOPE_AGENT);
                unsigned tgt = 32u * (unsigned)(s + 1);   // monotone, no reset
                while (__hip_atomic_load(ctr, __ATOMIC_RELAXED,
                                         __HIP_MEMORY_SCOPE_AGENT) < tgt)
                    __builtin_amdgcn_s_sleep(1);
            }
            __syncthreads();
        }
    }
}

// ---- workspace layout (bytes) ----
#define OFF_XBF    ((size_t)0)
#define OFF_WIHF   (OFF_XBF  + (size_t)TB * IN_ * 2)
#define OFF_WIHB   (OFF_WIHF + (size_t)G4 * IN_ * 2)
#define OFF_WHHF   (OFF_WIHB + (size_t)G4 * IN_ * 2)
#define OFF_WHHB   (OFF_WHHF + (size_t)G4 * HH * 2)
#define OFF_WLIN   (OFF_WHHB + (size_t)G4 * HH * 2)
#define OFF_BIASF  (OFF_WLIN + (size_t)OUTD * 2 * HH * 2)
#define OFF_BIASB  (OFF_BIASF + (size_t)G4 * 4)
#define OFF_XWF    (OFF_BIASB + (size_t)G4 * 4)
#define OFF_XWB    (OFF_XWF  + (size_t)TB * G4 * 2)
#define OFF_HCAT   (OFF_XWB  + (size_t)TB * G4 * 2)
#define OFF_CTR    (OFF_HCAT + (size_t)TB * 2 * HH * 2)
#define WS_NEED    (OFF_CTR  + (size_t)8 * 64 * 4)

extern "C" void kernel_launch(void* const* d_in, const int* in_sizes, int n_in,
                              void* d_out, int out_size, void* d_ws, size_t ws_size,
                              hipStream_t stream) {
    (void)in_sizes; (void)n_in; (void)out_size;
    if (ws_size < WS_NEED) return;

    const float* x    = (const float*)d_in[0];
    const float* Wihf = (const float*)d_in[1];
    const float* Whhf = (const float*)d_in[2];
    const float* bihf = (const float*)d_in[3];
    const float* bhhf = (const float*)d_in[4];
    const float* Wihb = (const float*)d_in[5];
    const float* Whhb = (const float*)d_in[6];
    const float* bihb = (const float*)d_in[7];
    const float* bhhb = (const float*)d_in[8];
    const float* Wlin = (const float*)d_in[9];
    const float* blin = (const float*)d_in[10];
    float* out = (float*)d_out;

    char* ws = (char*)d_ws;
    u16* x_bf    = (u16*)(ws + OFF_XBF);
    u16* wihf_bf = (u16*)(ws + OFF_WIHF);
    u16* wihb_bf = (u16*)(ws + OFF_WIHB);
    u16* whhf_bf = (u16*)(ws + OFF_WHHF);
    u16* whhb_bf = (u16*)(ws + OFF_WHHB);
    u16* wlin_bf = (u16*)(ws + OFF_WLIN);
    float* bias_f = (float*)(ws + OFF_BIASF);
    float* bias_b = (float*)(ws + OFF_BIASB);
    u16* xw_f = (u16*)(ws + OFF_XWF);
    u16* xw_b = (u16*)(ws + OFF_XWB);
    u16* hcat = (u16*)(ws + OFF_HCAT);
    unsigned* ctrs = (unsigned*)(ws + OFF_CTR);

    cvt_kernel<<<2048, 256, 0, stream>>>(x, x_bf, (TB * IN_) / 4);
    cvt_kernel<<<512, 256, 0, stream>>>(Wihf, wihf_bf, (G4 * IN_) / 4);
    cvt_kernel<<<512, 256, 0, stream>>>(Wihb, wihb_bf, (G4 * IN_) / 4);
    cvt_kernel<<<512, 256, 0, stream>>>(Whhf, whhf_bf, (G4 * HH) / 4);
    cvt_kernel<<<512, 256, 0, stream>>>(Whhb, whhb_bf, (G4 * HH) / 4);
    cvt_kernel<<<512, 256, 0, stream>>>(Wlin, wlin_bf, (OUTD * 2 * HH) / 4);
    bias_kernel<<<8, 256, 0, stream>>>(bihf, bhhf, bias_f, bihb, bhhb, bias_b, G4);

    // phase 1: xw = x @ W_ih^T + (b_ih + b_hh), bf16 out
    gemm_bias_kernel<<<dim3(TB / 128, G4 / 128), 256, 0, stream>>>(
        x_bf, wihf_bf, bias_f, xw_f, TB, G4, IN_, 1);
    gemm_bias_kernel<<<dim3(TB / 128, G4 / 128), 256, 0, stream>>>(
        x_bf, wihb_bf, bias_b, xw_b, TB, G4, IN_, 1);

    // phase 2: persistent recurrence (one launch, RMW barrier, no fences)
    (void)hipMemsetAsync(ctrs, 0, 8 * 64 * 4, stream);
    lstm_seq_kernel<<<256, 256, 0, stream>>>(xw_f, xw_b, whhf_bf, whhb_bf, hcat, ctrs);

    // phase 3: out = hcat @ W_lin^T + b_lin, fp32 out
    gemm_bias_kernel<<<dim3(TB / 128, OUTD / 128), 256, 0, stream>>>(
        hcat, wlin_bf, blin, out, TB, OUTD, 2 * HH, 0);
}